// Round 6
// baseline (5335.912 us; speedup 1.0000x reference)
//
#include <hip/hip_runtime.h>

#define Bb 32
#define Tt 512
#define Dd 256
#define Pp 512
#define Hh 512
#define G4 2048
#define TC 128   // time-chunk length (4 chunks)
#define NG 8     // batch groups (4 batches each), gid = blockIdx&7 -> XCD-local
#define WPG 32   // workgroups per group (grid = 256)
#define NBG 4    // batches per group

__device__ __forceinline__ float sigmf(float x){ return 1.0f/(1.0f+__expf(-x)); }
__device__ __forceinline__ float tanhf_(float x){ return 1.0f - 2.0f/(__expf(2.0f*x)+1.0f); }

// out[m] = sum_k A[m,k]^2
__global__ void k_rowsq(const float* __restrict__ A, float* __restrict__ o, int M, int K){
  int m = blockIdx.x*blockDim.x + threadIdx.x;
  if (m >= M) return;
  const float4* a4 = (const float4*)(A + (size_t)m*K);
  float s = 0.f;
  for (int i = 0; i < K/4; ++i){ float4 v = a4[i]; s += v.x*v.x + v.y*v.y + v.z*v.z + v.w*v.w; }
  o[m] = s;
}

// out (N x M) = in (M x N)^T
__global__ void k_transpose(const float* __restrict__ in, float* __restrict__ out, int M, int N){
  __shared__ float tile[32][33];
  int bn = blockIdx.x * 32;
  int bm = blockIdx.y * 32;
  int tx = threadIdx.x, ty = threadIdx.y; // block (32,8)
  #pragma unroll
  for (int i = 0; i < 32; i += 8)
    tile[ty+i][tx] = in[(size_t)(bm+ty+i)*N + bn+tx];
  __syncthreads();
  #pragma unroll
  for (int i = 0; i < 32; i += 8)
    out[(size_t)(bn+ty+i)*M + bm+tx] = tile[tx][ty+i];
}

// bx[r] = dot(W_ih[r,:], b_lin) + b_ih[r] + b_hh[r]
__global__ void k_bx(const float* __restrict__ Wih, const float* __restrict__ blin,
                     const float* __restrict__ bih, const float* __restrict__ bhh,
                     float* __restrict__ bx){
  int r = blockIdx.x*blockDim.x + threadIdx.x; // 2048 threads
  const float4* w4 = (const float4*)(Wih + (size_t)r*Hh);
  const float4* b4 = (const float4*)blin;
  float s = 0.f;
  for (int i = 0; i < Hh/4; ++i){ float4 w=w4[i], b=b4[i]; s += w.x*b.x+w.y*b.y+w.z*b.z+w.w*b.w; }
  bx[r] = s + bih[r] + bhh[r];
}

// Generic tiled fp32 GEMM: C[M,N] = epi(A[M,K] @ B[K,N])
// EPI 0: none. EPI 1: exp(-max(rowAux[m]+colAux[n]-2*acc,0)). EPI 2: acc+colAux[n].
// REMAP: A-row (and rowAux) index m -> (m>>7)*Tt + t0 + (m&127); C stays dense.
template<int EPI, bool REMAP>
__global__ __launch_bounds__(256) void k_gemm(const float* __restrict__ A, const float* __restrict__ Bm,
                                              float* __restrict__ C, int M, int N, int K,
                                              const float* __restrict__ rowAux,
                                              const float* __restrict__ colAux, int t0)
{
  __shared__ float As[16][132];
  __shared__ float Bs[16][68];
  const int tid = threadIdx.x;
  const int bm = blockIdx.x * 128;
  const int bn = blockIdx.y * 64;
  const int tm = (tid & 15) * 8;
  const int tn = (tid >> 4) * 4;
  const int arow = tid >> 1;
  const int akq  = (tid & 1) * 8;
  const int brow = tid >> 4;
  const int bcol = (tid & 15) * 4;
  const int am = bm + arow;
  const size_t aRow = REMAP ? ((size_t)(am >> 7) * Tt + t0 + (am & 127)) : (size_t)am;
  float acc[8][4] = {};
  for (int k0 = 0; k0 < K; k0 += 16){
    float4 a0 = *(const float4*)&A[aRow*K + k0 + akq];
    float4 a1 = *(const float4*)&A[aRow*K + k0 + akq + 4];
    float4 bv = *(const float4*)&Bm[(size_t)(k0 + brow)*N + bn + bcol];
    As[akq+0][arow]=a0.x; As[akq+1][arow]=a0.y; As[akq+2][arow]=a0.z; As[akq+3][arow]=a0.w;
    As[akq+4][arow]=a1.x; As[akq+5][arow]=a1.y; As[akq+6][arow]=a1.z; As[akq+7][arow]=a1.w;
    *(float4*)&Bs[brow][bcol] = bv;
    __syncthreads();
    #pragma unroll
    for (int kk = 0; kk < 16; ++kk){
      float4 x0 = *(const float4*)&As[kk][tm];
      float4 x1 = *(const float4*)&As[kk][tm+4];
      float4 y  = *(const float4*)&Bs[kk][tn];
      float av[8] = {x0.x,x0.y,x0.z,x0.w,x1.x,x1.y,x1.z,x1.w};
      #pragma unroll
      for (int i=0;i<8;++i){
        float a = av[i];
        acc[i][0] += a*y.x; acc[i][1] += a*y.y; acc[i][2] += a*y.z; acc[i][3] += a*y.w;
      }
    }
    __syncthreads();
  }
  #pragma unroll
  for (int i=0;i<8;++i){
    int m = bm + tm + i;
    size_t mAux = REMAP ? ((size_t)(m >> 7) * Tt + t0 + (m & 127)) : (size_t)m;
    float4 o;
    float vv[4];
    #pragma unroll
    for (int j=0;j<4;++j){
      int n = bn + tn + j;
      float v = acc[i][j];
      if (EPI==1)      v = __expf(-fmaxf(rowAux[mAux] + colAux[n] - 2.f*v, 0.f));
      else if (EPI==2) v = v + colAux[n];
      vv[j] = v;
    }
    o.x=vv[0]; o.y=vv[1]; o.z=vv[2]; o.w=vv[3];
    *(float4*)&C[(size_t)m*N + bn + tn] = o;
  }
}

// Persistent LSTM over one time-chunk of TC steps.
// Grid: 256 WGs x 512 thr, cooperative. Group gid = blockIdx&7 owns batches
// [4gid,4gid+4); its 32 WGs all land on XCD gid under %8 round-robin (speed
// heuristic only). wg = blockIdx>>3 owns j in [wg*16, wg*16+16).
// Thread: wave wv, lane. ks = lane>>2 (16 k-slices of 32); rowgrp = jloc =
// (wv&3)*4 + (lane&3); bh = wv>>2 (2 batches each). W[4][32]: ALL 4 gate rows
// of j = wg*16+jloc, k-slice [32ks,32ks+32) -> after ks-reduction each thread
// holds all 4 gates of its j (no gate-gather shuffles). 64 LDS floats/thread.
// Sync (r5-proven): relaxed poll + ONE acquire fence; producer __syncthreads
// (vmcnt drain) + ONE release fence + relaxed flag store.
__global__ __launch_bounds__(512) __attribute__((amdgpu_waves_per_eu(2, 2)))
void k_lstm_persist(const float* __restrict__ Whh, const float* __restrict__ xs,
                    float* __restrict__ cbuf, float* __restrict__ out,
                    unsigned* __restrict__ flags, int t0)
{
  __shared__ float hbuf[NBG][16][36];   // [batch][ks][32+4 pad] ~9.2 KB
  const int tid  = threadIdx.x;
  const int lane = tid & 63;
  const int wv   = tid >> 6;
  const int bh   = wv >> 2;                      // batch half: 0 or 1
  const int ks   = lane >> 2;                    // 0..15
  const int jloc = (wv & 3)*4 + (lane & 3);      // 0..15
  const int gid  = blockIdx.x & 7;
  const int wg   = blockIdx.x >> 3;              // 0..31
  const int j    = wg*16 + jloc;
  const int b0   = gid*NBG + bh*2;               // this thread's two batches

  // ---- load W: all 4 gate rows of j, k-slice [32ks, 32ks+32) ----
  float W[4][32];
  #pragma unroll
  for (int r = 0; r < 4; ++r){
    const float* wr = &Whh[((size_t)(r*Hh + j))*Hh + ks*32];
    #pragma unroll
    for (int c = 0; c < 8; ++c){
      float4 w = *(const float4*)&wr[c*4];
      W[r][c*4+0]=w.x; W[r][c*4+1]=w.y; W[r][c*4+2]=w.z; W[r][c*4+3]=w.w;
    }
  }
  #pragma unroll
  for (int r = 0; r < 4; ++r)
    #pragma unroll
    for (int c = 0; c < 32; ++c)
      asm volatile("" : "+v"(W[r][c]));

  // c-state for (b0,j),(b0+1,j): valid on all lanes (redundant copies)
  float c0 = 0.f, c1 = 0.f;
  if (t0 != 0){
    c0 = cbuf[(size_t)(b0+0)*Hh + j];
    c1 = cbuf[(size_t)(b0+1)*Hh + j];
  }

  // h-stage identity: 2048 floats over 512 threads (float4 each)
  const int sbl = tid >> 7;            // 0..3 batch-local
  const int skk = (tid & 127) * 4;     // k base
  const int sq  = skk >> 5, sr = skk & 31;

  for (int tl = 0; tl < TC; ++tl){
    const int t = t0 + tl;

    // prefetch xs for this step (independent of h); only gate-owner lanes
    float xq[4][2];
    if (ks == 0){
      const size_t r0 = ((size_t)(b0+0)*TC + tl)*G4 + j;
      const size_t r1 = ((size_t)(b0+1)*TC + tl)*G4 + j;
      #pragma unroll
      for (int g = 0; g < 4; ++g){
        xq[g][0] = xs[r0 + g*Hh];
        xq[g][1] = xs[r1 + g*Hh];
      }
    }

    // ---- wait for all 32 producers of this group (relaxed poll + 1 acquire) ----
    if (t > 0){
      if (wv == 0){
        const unsigned tgt = (unsigned)t;
        unsigned f;
        for (;;){
          f = (lane < WPG)
              ? __hip_atomic_load(&flags[gid*WPG + lane], __ATOMIC_RELAXED, __HIP_MEMORY_SCOPE_AGENT)
              : tgt;
          if (__all((int)(f >= tgt))) break;
        }
        __builtin_amdgcn_fence(__ATOMIC_ACQUIRE, "agent");   // one inv per WG per step
      }
      __syncthreads();
    }

    // ---- stage h(t-1) into LDS ----
    float4 hv = {0.f,0.f,0.f,0.f};
    if (t > 0){
      const float* src = &out[((size_t)(gid*NBG + sbl)*Tt + (t-1))*Hh + skk];
      hv.x = __hip_atomic_load(src+0, __ATOMIC_RELAXED, __HIP_MEMORY_SCOPE_AGENT);
      hv.y = __hip_atomic_load(src+1, __ATOMIC_RELAXED, __HIP_MEMORY_SCOPE_AGENT);
      hv.z = __hip_atomic_load(src+2, __ATOMIC_RELAXED, __HIP_MEMORY_SCOPE_AGENT);
      hv.w = __hip_atomic_load(src+3, __ATOMIC_RELAXED, __HIP_MEMORY_SCOPE_AGENT);
    }
    *(float4*)&hbuf[sbl][sq][sr] = hv;
    __syncthreads();

    // ---- GEMV: 4 gate rows x 32 k x 2 batches = 256 FMA, 16 ds_read_b128 ----
    float acc[4][2];
    #pragma unroll
    for (int r=0;r<4;++r){ acc[r][0]=0.f; acc[r][1]=0.f; }
    {
      const float* hA = &hbuf[bh*2+0][ks][0];
      const float* hB = &hbuf[bh*2+1][ks][0];
      #pragma unroll
      for (int c = 0; c < 8; ++c){
        float4 p = *(const float4*)&hA[c*4];
        float4 q = *(const float4*)&hB[c*4];
        #pragma unroll
        for (int r = 0; r < 4; ++r){
          acc[r][0] = fmaf(W[r][c*4+0],p.x,acc[r][0]); acc[r][0] = fmaf(W[r][c*4+1],p.y,acc[r][0]);
          acc[r][0] = fmaf(W[r][c*4+2],p.z,acc[r][0]); acc[r][0] = fmaf(W[r][c*4+3],p.w,acc[r][0]);
          acc[r][1] = fmaf(W[r][c*4+0],q.x,acc[r][1]); acc[r][1] = fmaf(W[r][c*4+1],q.y,acc[r][1]);
          acc[r][1] = fmaf(W[r][c*4+2],q.z,acc[r][1]); acc[r][1] = fmaf(W[r][c*4+3],q.w,acc[r][1]);
        }
      }
    }
    // reduce over ks (lane bits 2..5)
    #pragma unroll
    for (int m = 4; m <= 32; m <<= 1){
      #pragma unroll
      for (int r=0;r<4;++r){
        acc[r][0] += __shfl_xor(acc[r][0], m, 64);
        acc[r][1] += __shfl_xor(acc[r][1], m, 64);
      }
    }

    // ---- gates + state update + h store (gate-owner lanes only) ----
    if (ks == 0){
      float gi0 = sigmf (acc[0][0] + xq[0][0]);
      float gf0 = sigmf (acc[1][0] + xq[1][0]);
      float gg0 = tanhf_(acc[2][0] + xq[2][0]);
      float go0 = sigmf (acc[3][0] + xq[3][0]);
      float gi1 = sigmf (acc[0][1] + xq[0][1]);
      float gf1 = sigmf (acc[1][1] + xq[1][1]);
      float gg1 = tanhf_(acc[2][1] + xq[2][1]);
      float go1 = sigmf (acc[3][1] + xq[3][1]);
      c0 = gf0*c0 + gi0*gg0;
      c1 = gf1*c1 + gi1*gg1;
      float h0 = go0 * tanhf_(c0);
      float h1 = go1 * tanhf_(c1);
      __hip_atomic_store(&out[((size_t)(b0+0)*Tt + t)*Hh + j], h0,
                         __ATOMIC_RELAXED, __HIP_MEMORY_SCOPE_AGENT);
      __hip_atomic_store(&out[((size_t)(b0+1)*Tt + t)*Hh + j], h1,
                         __ATOMIC_RELAXED, __HIP_MEMORY_SCOPE_AGENT);
    }
    __syncthreads();   // every wave drains vmcnt -> all h-stores complete

    // ---- publish: ONE release fence + relaxed flag store ----
    if (tid == 0){
      __builtin_amdgcn_fence(__ATOMIC_RELEASE, "agent");
      __hip_atomic_store(&flags[gid*WPG + wg], (unsigned)(t + 1),
                         __ATOMIC_RELAXED, __HIP_MEMORY_SCOPE_AGENT);
    }
  }

  if (ks == 0){
    cbuf[(size_t)(b0+0)*Hh + j] = c0;
    cbuf[(size_t)(b0+1)*Hh + j] = c1;
  }
}

extern "C" void kernel_launch(void* const* d_in, const int* in_sizes, int n_in,
                              void* d_out, int out_size, void* d_ws, size_t ws_size,
                              hipStream_t stream)
{
  const float* x    = (const float*)d_in[0];
  const float* prot = (const float*)d_in[1];
  const float* Wlin = (const float*)d_in[2];
  const float* blin = (const float*)d_in[3];
  const float* Wih  = (const float*)d_in[4];
  const float* Whh  = (const float*)d_in[5];
  const float* bih  = (const float*)d_in[6];
  const float* bhh  = (const float*)d_in[7];
  float* out = (float*)d_out;
  float* ws  = (float*)d_ws;

  size_t off = 0;
  auto alloc = [&](size_t n)->float*{ float* p = ws + off; off += (n + 15) & ~((size_t)15); return p; };
  float* x2    = alloc((size_t)Bb*Tt);
  float* p2    = alloc(Pp);
  float* pT    = alloc((size_t)Dd*Pp);
  float* bx    = alloc(G4);
  float* Wx    = alloc((size_t)G4*Pp);
  float* WxT   = alloc((size_t)Pp*G4);
  float* cbuf  = alloc((size_t)Bb*Hh);
  float* featsC= alloc((size_t)Bb*TC*Pp);
  float* xsC   = alloc((size_t)Bb*TC*G4);
  unsigned* flags = (unsigned*)alloc(NG*WPG);
  // total ~13.6M floats ~ 55 MB

  // ---- setup ----
  k_rowsq<<<dim3((Bb*Tt)/256), dim3(256), 0, stream>>>(x, x2, Bb*Tt, Dd);
  k_rowsq<<<dim3(Pp/256), dim3(256), 0, stream>>>(prot, p2, Pp, Dd);
  k_transpose<<<dim3(Dd/32, Pp/32), dim3(32,8), 0, stream>>>(prot, pT, Pp, Dd);
  k_bx<<<dim3(G4/256), dim3(256), 0, stream>>>(Wih, blin, bih, bhh, bx);
  k_gemm<0,false><<<dim3(G4/128, Pp/64), dim3(256), 0, stream>>>(Wih, Wlin, Wx, G4, Pp, Hh, nullptr, nullptr, 0);
  k_transpose<<<dim3(Pp/32, G4/32), dim3(32,8), 0, stream>>>(Wx, WxT, G4, Pp);
  hipMemsetAsync(flags, 0, NG*WPG*sizeof(unsigned), stream);   // reset every launch (in-graph)

  // ---- main: 4 time-chunks of 128 steps ----
  for (int ch = 0; ch < Tt/TC; ++ch){
    int t0 = ch * TC;
    k_gemm<1,true><<<dim3((Bb*TC)/128, Pp/64), dim3(256), 0, stream>>>(
        x, pT, featsC, Bb*TC, Pp, Dd, x2, p2, t0);
    k_gemm<2,false><<<dim3((Bb*TC)/128, G4/64), dim3(256), 0, stream>>>(
        featsC, WxT, xsC, Bb*TC, G4, Pp, nullptr, bx, 0);
    void* args[] = { (void*)&Whh, (void*)&xsC, (void*)&cbuf, (void*)&out, (void*)&flags, (void*)&t0 };
    hipLaunchCooperativeKernel((void*)k_lstm_persist, dim3(NG*WPG), dim3(512), args, 0, stream);
  }
}

// Round 7
// 4943.206 us; speedup vs baseline: 1.0794x; 1.0794x over previous
//
#include <hip/hip_runtime.h>

#define Bb 32
#define Tt 512
#define Dd 256
#define Pp 512
#define Hh 512
#define G4 2048
#define TC 128   // time-chunk length (4 chunks)
#define NG 8     // batch groups (4 batches each); gid = blockIdx&7 -> XCD-local
#define WPG 16   // workgroups per group (grid = 128: ONE group per XCD)
#define NBG 4    // batches per group

__device__ __forceinline__ float sigmf(float x){ return 1.0f/(1.0f+__expf(-x)); }
__device__ __forceinline__ float tanhf_(float x){ return 1.0f - 2.0f/(__expf(2.0f*x)+1.0f); }

// out[m] = sum_k A[m,k]^2
__global__ void k_rowsq(const float* __restrict__ A, float* __restrict__ o, int M, int K){
  int m = blockIdx.x*blockDim.x + threadIdx.x;
  if (m >= M) return;
  const float4* a4 = (const float4*)(A + (size_t)m*K);
  float s = 0.f;
  for (int i = 0; i < K/4; ++i){ float4 v = a4[i]; s += v.x*v.x + v.y*v.y + v.z*v.z + v.w*v.w; }
  o[m] = s;
}

// out (N x M) = in (M x N)^T
__global__ void k_transpose(const float* __restrict__ in, float* __restrict__ out, int M, int N){
  __shared__ float tile[32][33];
  int bn = blockIdx.x * 32;
  int bm = blockIdx.y * 32;
  int tx = threadIdx.x, ty = threadIdx.y; // block (32,8)
  #pragma unroll
  for (int i = 0; i < 32; i += 8)
    tile[ty+i][tx] = in[(size_t)(bm+ty+i)*N + bn+tx];
  __syncthreads();
  #pragma unroll
  for (int i = 0; i < 32; i += 8)
    out[(size_t)(bn+ty+i)*M + bm+tx] = tile[tx][ty+i];
}

// bx[r] = dot(W_ih[r,:], b_lin) + b_ih[r] + b_hh[r]
__global__ void k_bx(const float* __restrict__ Wih, const float* __restrict__ blin,
                     const float* __restrict__ bih, const float* __restrict__ bhh,
                     float* __restrict__ bx){
  int r = blockIdx.x*blockDim.x + threadIdx.x; // 2048 threads
  const float4* w4 = (const float4*)(Wih + (size_t)r*Hh);
  const float4* b4 = (const float4*)blin;
  float s = 0.f;
  for (int i = 0; i < Hh/4; ++i){ float4 w=w4[i], b=b4[i]; s += w.x*b.x+w.y*b.y+w.z*b.z+w.w*b.w; }
  bx[r] = s + bih[r] + bhh[r];
}

// Generic tiled fp32 GEMM: C[M,N] = epi(A[M,K] @ B[K,N])
// EPI 0: none. EPI 1: exp(-max(rowAux[m]+colAux[n]-2*acc,0)). EPI 2: acc+colAux[n].
// REMAP: A-row (and rowAux) index m -> (m>>7)*Tt + t0 + (m&127); C stays dense.
template<int EPI, bool REMAP>
__global__ __launch_bounds__(256) void k_gemm(const float* __restrict__ A, const float* __restrict__ Bm,
                                              float* __restrict__ C, int M, int N, int K,
                                              const float* __restrict__ rowAux,
                                              const float* __restrict__ colAux, int t0)
{
  __shared__ float As[16][132];
  __shared__ float Bs[16][68];
  const int tid = threadIdx.x;
  const int bm = blockIdx.x * 128;
  const int bn = blockIdx.y * 64;
  const int tm = (tid & 15) * 8;
  const int tn = (tid >> 4) * 4;
  const int arow = tid >> 1;
  const int akq  = (tid & 1) * 8;
  const int brow = tid >> 4;
  const int bcol = (tid & 15) * 4;
  const int am = bm + arow;
  const size_t aRow = REMAP ? ((size_t)(am >> 7) * Tt + t0 + (am & 127)) : (size_t)am;
  float acc[8][4] = {};
  for (int k0 = 0; k0 < K; k0 += 16){
    float4 a0 = *(const float4*)&A[aRow*K + k0 + akq];
    float4 a1 = *(const float4*)&A[aRow*K + k0 + akq + 4];
    float4 bv = *(const float4*)&Bm[(size_t)(k0 + brow)*N + bn + bcol];
    As[akq+0][arow]=a0.x; As[akq+1][arow]=a0.y; As[akq+2][arow]=a0.z; As[akq+3][arow]=a0.w;
    As[akq+4][arow]=a1.x; As[akq+5][arow]=a1.y; As[akq+6][arow]=a1.z; As[akq+7][arow]=a1.w;
    *(float4*)&Bs[brow][bcol] = bv;
    __syncthreads();
    #pragma unroll
    for (int kk = 0; kk < 16; ++kk){
      float4 x0 = *(const float4*)&As[kk][tm];
      float4 x1 = *(const float4*)&As[kk][tm+4];
      float4 y  = *(const float4*)&Bs[kk][tn];
      float av[8] = {x0.x,x0.y,x0.z,x0.w,x1.x,x1.y,x1.z,x1.w};
      #pragma unroll
      for (int i=0;i<8;++i){
        float a = av[i];
        acc[i][0] += a*y.x; acc[i][1] += a*y.y; acc[i][2] += a*y.z; acc[i][3] += a*y.w;
      }
    }
    __syncthreads();
  }
  #pragma unroll
  for (int i=0;i<8;++i){
    int m = bm + tm + i;
    size_t mAux = REMAP ? ((size_t)(m >> 7) * Tt + t0 + (m & 127)) : (size_t)m;
    float4 o;
    float vv[4];
    #pragma unroll
    for (int j=0;j<4;++j){
      int n = bn + tn + j;
      float v = acc[i][j];
      if (EPI==1)      v = __expf(-fmaxf(rowAux[mAux] + colAux[n] - 2.f*v, 0.f));
      else if (EPI==2) v = v + colAux[n];
      vv[j] = v;
    }
    o.x=vv[0]; o.y=vv[1]; o.z=vv[2]; o.w=vv[3];
    *(float4*)&C[(size_t)m*N + bn + tn] = o;
  }
}

// Persistent LSTM over one time-chunk of TC steps.
// MEASURED-OPTIMAL GEOMETRY (r2): grid 128 x 512 thr, cooperative.
// Group gid = blockIdx&7 owns batches [4gid,4gid+4); its 16 WGs land on XCD
// gid under %8 round-robin (speed heuristic; correctness from protocol).
// wg = blockIdx>>3 owns j in [wg*32, wg*32+32).
// Thread: ks = lane>>2 (16 k-slices of 32), jloc = wv*4 + (lane&3) -> thread
// holds ALL 4 gate rows of j = wg*32+jloc over k-slice [32ks,32ks+32):
// W[4][32] = 128 VGPRs (pinned). After ks-reduction, ks==0 lanes own all 4
// gates of (j, all 4 batches) -> no gate-gather shuffles.
// Sync (r5-proven protocol): relaxed flag poll + ONE acquire fence;
// producer __syncthreads (vmcnt drain) + ONE release fence + relaxed store.
__global__ __launch_bounds__(512) __attribute__((amdgpu_waves_per_eu(2, 2)))
void k_lstm_persist(const float* __restrict__ Whh, const float* __restrict__ xs,
                    float* __restrict__ cbuf, float* __restrict__ out,
                    unsigned* __restrict__ flags, int t0)
{
  __shared__ float hbuf[NBG][16][36];   // [batch][ks][32+4 pad] ~9.2 KB
  const int tid  = threadIdx.x;
  const int lane = tid & 63;
  const int wv   = tid >> 6;
  const int ks   = lane >> 2;                    // 0..15
  const int jloc = wv*4 + (lane & 3);            // 0..31
  const int gid  = blockIdx.x & 7;
  const int wg   = blockIdx.x >> 3;              // 0..15
  const int j    = wg*32 + jloc;
  const int b0   = gid*NBG;                      // 4 batches of this group

  // ---- load W: all 4 gate rows of j, k-slice [32ks, 32ks+32) ----
  float W[4][32];
  #pragma unroll
  for (int r = 0; r < 4; ++r){
    const float* wr = &Whh[((size_t)(r*Hh + j))*Hh + ks*32];
    #pragma unroll
    for (int c = 0; c < 8; ++c){
      float4 w = *(const float4*)&wr[c*4];
      W[r][c*4+0]=w.x; W[r][c*4+1]=w.y; W[r][c*4+2]=w.z; W[r][c*4+3]=w.w;
    }
  }
  #pragma unroll
  for (int r = 0; r < 4; ++r)
    #pragma unroll
    for (int c = 0; c < 32; ++c)
      asm volatile("" : "+v"(W[r][c]));

  // c-state for (b0..b0+3, j): used on ks==0 lanes only (loaded redundantly)
  float c_st[NBG] = {0.f,0.f,0.f,0.f};
  if (t0 != 0){
    #pragma unroll
    for (int bl = 0; bl < NBG; ++bl)
      c_st[bl] = cbuf[(size_t)(b0+bl)*Hh + j];
  }

  // h-stage identity: 2048 floats over 512 threads (float4 each)
  const int sbl = tid >> 7;            // 0..3 batch-local
  const int skk = (tid & 127) * 4;     // k base
  const int sq  = skk >> 5, sr = skk & 31;

  for (int tl = 0; tl < TC; ++tl){
    const int t = t0 + tl;

    // prefetch xs for this step (gate-owner lanes only; independent of h)
    float xq[4][NBG];
    if (ks == 0){
      #pragma unroll
      for (int bl = 0; bl < NBG; ++bl){
        const size_t rr = ((size_t)(b0+bl)*TC + tl)*G4 + j;
        #pragma unroll
        for (int g = 0; g < 4; ++g)
          xq[g][bl] = xs[rr + g*Hh];
      }
    }

    // ---- wait for the 16 producers of this group (relaxed poll + 1 acquire) ----
    if (t > 0){
      if (wv == 0){
        const unsigned tgt = (unsigned)t;
        for (;;){
          unsigned f = (lane < WPG)
              ? __hip_atomic_load(&flags[gid*WPG + lane], __ATOMIC_RELAXED, __HIP_MEMORY_SCOPE_AGENT)
              : tgt;
          if (__all((int)(f >= tgt))) break;
        }
        __builtin_amdgcn_fence(__ATOMIC_ACQUIRE, "agent");   // one inv per WG per step
      }
      __syncthreads();
    }

    // ---- stage h(t-1) into LDS ----
    float4 hv = {0.f,0.f,0.f,0.f};
    if (t > 0){
      const float* src = &out[((size_t)(b0 + sbl)*Tt + (t-1))*Hh + skk];
      hv.x = __hip_atomic_load(src+0, __ATOMIC_RELAXED, __HIP_MEMORY_SCOPE_AGENT);
      hv.y = __hip_atomic_load(src+1, __ATOMIC_RELAXED, __HIP_MEMORY_SCOPE_AGENT);
      hv.z = __hip_atomic_load(src+2, __ATOMIC_RELAXED, __HIP_MEMORY_SCOPE_AGENT);
      hv.w = __hip_atomic_load(src+3, __ATOMIC_RELAXED, __HIP_MEMORY_SCOPE_AGENT);
    }
    *(float4*)&hbuf[sbl][sq][sr] = hv;
    __syncthreads();

    // ---- GEMV: 4 gate rows x 32 k x 4 batches = 512 FMA, 32 ds_read_b128 ----
    float acc[4][NBG];
    #pragma unroll
    for (int r=0;r<4;++r)
      #pragma unroll
      for (int bl=0;bl<NBG;++bl) acc[r][bl]=0.f;
    #pragma unroll
    for (int bl = 0; bl < NBG; ++bl){
      const float* hb = &hbuf[bl][ks][0];
      #pragma unroll
      for (int c = 0; c < 8; ++c){
        float4 p = *(const float4*)&hb[c*4];
        #pragma unroll
        for (int r = 0; r < 4; ++r){
          acc[r][bl] = fmaf(W[r][c*4+0],p.x,acc[r][bl]);
          acc[r][bl] = fmaf(W[r][c*4+1],p.y,acc[r][bl]);
          acc[r][bl] = fmaf(W[r][c*4+2],p.z,acc[r][bl]);
          acc[r][bl] = fmaf(W[r][c*4+3],p.w,acc[r][bl]);
        }
      }
    }
    // reduce over ks (lane bits 2..5)
    #pragma unroll
    for (int m = 4; m <= 32; m <<= 1){
      #pragma unroll
      for (int r=0;r<4;++r)
        #pragma unroll
        for (int bl=0;bl<NBG;++bl)
          acc[r][bl] += __shfl_xor(acc[r][bl], m, 64);
    }

    // ---- gates + state update + h store (gate-owner lanes: ks==0) ----
    if (ks == 0){
      #pragma unroll
      for (int bl = 0; bl < NBG; ++bl){
        float gi = sigmf (acc[0][bl] + xq[0][bl]);
        float gf = sigmf (acc[1][bl] + xq[1][bl]);
        float gg = tanhf_(acc[2][bl] + xq[2][bl]);
        float go = sigmf (acc[3][bl] + xq[3][bl]);
        c_st[bl] = gf*c_st[bl] + gi*gg;
        float h = go * tanhf_(c_st[bl]);
        __hip_atomic_store(&out[((size_t)(b0+bl)*Tt + t)*Hh + j], h,
                           __ATOMIC_RELAXED, __HIP_MEMORY_SCOPE_AGENT);
      }
    }
    __syncthreads();   // every wave drains vmcnt -> all h-stores complete

    // ---- publish: ONE release fence + relaxed flag store ----
    if (tid == 0){
      __builtin_amdgcn_fence(__ATOMIC_RELEASE, "agent");
      __hip_atomic_store(&flags[gid*WPG + wg], (unsigned)(t + 1),
                         __ATOMIC_RELAXED, __HIP_MEMORY_SCOPE_AGENT);
    }
  }

  if (ks == 0){
    #pragma unroll
    for (int bl = 0; bl < NBG; ++bl)
      cbuf[(size_t)(b0+bl)*Hh + j] = c_st[bl];
  }
}

extern "C" void kernel_launch(void* const* d_in, const int* in_sizes, int n_in,
                              void* d_out, int out_size, void* d_ws, size_t ws_size,
                              hipStream_t stream)
{
  const float* x    = (const float*)d_in[0];
  const float* prot = (const float*)d_in[1];
  const float* Wlin = (const float*)d_in[2];
  const float* blin = (const float*)d_in[3];
  const float* Wih  = (const float*)d_in[4];
  const float* Whh  = (const float*)d_in[5];
  const float* bih  = (const float*)d_in[6];
  const float* bhh  = (const float*)d_in[7];
  float* out = (float*)d_out;
  float* ws  = (float*)d_ws;

  size_t off = 0;
  auto alloc = [&](size_t n)->float*{ float* p = ws + off; off += (n + 15) & ~((size_t)15); return p; };
  float* x2    = alloc((size_t)Bb*Tt);
  float* p2    = alloc(Pp);
  float* pT    = alloc((size_t)Dd*Pp);
  float* bx    = alloc(G4);
  float* Wx    = alloc((size_t)G4*Pp);
  float* WxT   = alloc((size_t)Pp*G4);
  float* cbuf  = alloc((size_t)Bb*Hh);
  float* featsC= alloc((size_t)Bb*TC*Pp);
  float* xsC   = alloc((size_t)Bb*TC*G4);
  unsigned* flags = (unsigned*)alloc(NG*WPG);
  // total ~13.6M floats ~ 55 MB

  // ---- setup ----
  k_rowsq<<<dim3((Bb*Tt)/256), dim3(256), 0, stream>>>(x, x2, Bb*Tt, Dd);
  k_rowsq<<<dim3(Pp/256), dim3(256), 0, stream>>>(prot, p2, Pp, Dd);
  k_transpose<<<dim3(Dd/32, Pp/32), dim3(32,8), 0, stream>>>(prot, pT, Pp, Dd);
  k_bx<<<dim3(G4/256), dim3(256), 0, stream>>>(Wih, blin, bih, bhh, bx);
  k_gemm<0,false><<<dim3(G4/128, Pp/64), dim3(256), 0, stream>>>(Wih, Wlin, Wx, G4, Pp, Hh, nullptr, nullptr, 0);
  k_transpose<<<dim3(Pp/32, G4/32), dim3(32,8), 0, stream>>>(Wx, WxT, G4, Pp);
  hipMemsetAsync(flags, 0, NG*WPG*sizeof(unsigned), stream);   // reset every launch (in-graph)

  // ---- main: 4 time-chunks of 128 steps ----
  for (int ch = 0; ch < Tt/TC; ++ch){
    int t0 = ch * TC;
    k_gemm<1,true><<<dim3((Bb*TC)/128, Pp/64), dim3(256), 0, stream>>>(
        x, pT, featsC, Bb*TC, Pp, Dd, x2, p2, t0);
    k_gemm<2,false><<<dim3((Bb*TC)/128, G4/64), dim3(256), 0, stream>>>(
        featsC, WxT, xsC, Bb*TC, G4, Pp, nullptr, bx, 0);
    void* args[] = { (void*)&Whh, (void*)&xsC, (void*)&cbuf, (void*)&out, (void*)&flags, (void*)&t0 };
    hipLaunchCooperativeKernel((void*)k_lstm_persist, dim3(NG*WPG), dim3(512), args, 0, stream);
  }
}